// Round 4
// baseline (1163.873 us; speedup 1.0000x reference)
//
#include <hip/hip_runtime.h>
#include <cstdint>
#include <cfloat>
#include <cstddef>

#define C_   128
#define CH   64
#define B_   8
#define S_   6
#define H_   128
#define W_   192
#define HW   (H_*W_)          /* 24576 */
#define SHW  (S_*HW)          /* 147456 */
#define NPIX (B_*SHW)         /* 1179648 */
#define KTOP 100
#define CAP  6144
#define NEGV (-1e9f)
#define EPSV (1e-6f)

// ---------------------------------------------------------------------------
// K1: resp[b,s,y,x] = sigma[s]^2 * ( w2 . relu(W1 @ feat + b1) + b2 )
// 2 pixels per thread (float2 loads), W1 transposed in LDS for broadcast reads.
// ---------------------------------------------------------------------------
__global__ __launch_bounds__(256) void resp_kernel(
    const float* __restrict__ feats, const float* __restrict__ sigma,
    const float* __restrict__ w1, const float* __restrict__ b1,
    const float* __restrict__ w2, const float* __restrict__ b2,
    float* __restrict__ resp)
{
    __shared__ float w1t[C_ * CH];   // [c][o]
    __shared__ float b1s[CH];
    __shared__ float w2s[CH];

    for (int i = threadIdx.x; i < C_ * CH; i += 256) {
        int o = i & (CH - 1);
        int c = i >> 6;
        w1t[i] = w1[o * C_ + c];
    }
    if (threadIdx.x < CH) {
        b1s[threadIdx.x] = b1[threadIdx.x];
        w2s[threadIdx.x] = w2[threadIdx.x];
    }
    __syncthreads();

    const int plane = blockIdx.x / 48;              // b*S + s
    const int p0    = (blockIdx.x % 48) * 512 + threadIdx.x * 2;
    const float* fp = feats + (size_t)plane * (size_t)(C_ * HW) + p0;

    float2 acc[CH];
#pragma unroll
    for (int o = 0; o < CH; ++o) { acc[o].x = 0.f; acc[o].y = 0.f; }

#pragma unroll 2
    for (int c = 0; c < C_; ++c) {
        const float2 f = *reinterpret_cast<const float2*>(fp + c * HW);
#pragma unroll
        for (int o = 0; o < CH; o += 4) {
            const float4 w = *reinterpret_cast<const float4*>(&w1t[(c << 6) + o]);
            acc[o + 0].x += w.x * f.x;  acc[o + 0].y += w.x * f.y;
            acc[o + 1].x += w.y * f.x;  acc[o + 1].y += w.y * f.y;
            acc[o + 2].x += w.z * f.x;  acc[o + 2].y += w.z * f.y;
            acc[o + 3].x += w.w * f.x;  acc[o + 3].y += w.w * f.y;
        }
    }

    const float b2v = b2[0];
    float rx = b2v, ry = b2v;
#pragma unroll
    for (int o = 0; o < CH; ++o) {
        float hx = fmaxf(acc[o].x + b1s[o], 0.f);
        float hy = fmaxf(acc[o].y + b1s[o], 0.f);
        rx += w2s[o] * hx;
        ry += w2s[o] * hy;
    }
    const int   s   = plane % S_;
    const float sg  = sigma[s];
    const float sg2 = sg * sg;
    float2 outv; outv.x = rx * sg2; outv.y = ry * sg2;
    *reinterpret_cast<float2*>(resp + (size_t)plane * HW + p0) = outv;
}

// ---------------------------------------------------------------------------
// K2: 3x3x3 local max (NEG padding) -> peak candidates per batch
// ---------------------------------------------------------------------------
__global__ __launch_bounds__(256) void peak_kernel(
    const float* __restrict__ resp, int* __restrict__ counts,
    float* __restrict__ cscore, int* __restrict__ cidx)
{
    const int gid = blockIdx.x * 256 + threadIdx.x;   // grid covers NPIX exactly
    const int b   = gid / SHW;
    const int rem = gid - b * SHW;
    const int s   = rem / HW;
    const int p   = rem - s * HW;
    const int y   = p / W_;
    const int x   = p - y * W_;

    const float v = resp[gid];
    if (!(v > 0.f)) return;                 // is_peak requires resp > 0

    float m = NEGV;
    for (int ds = -1; ds <= 1; ++ds) {
        const int ss = s + ds;
        if (ss < 0 || ss >= S_) continue;   // NEG padding: contributes nothing
        for (int dy = -1; dy <= 1; ++dy) {
            const int yy = y + dy;
            if (yy < 0 || yy >= H_) continue;
            for (int dx = -1; dx <= 1; ++dx) {
                const int xx = x + dx;
                if (xx < 0 || xx >= W_) continue;
                m = fmaxf(m, resp[(b * S_ + ss) * HW + yy * W_ + xx]);
            }
        }
    }
    // m includes v itself, so m >= v and |v - m| = m - v
    if (m - v < EPSV) {
        const int pos = atomicAdd(&counts[b], 1);
        if (pos < CAP) {
            cscore[b * CAP + pos] = v;
            cidx[b * CAP + pos]   = s * HW + p;
        }
    }
}

// ---------------------------------------------------------------------------
// K3: per-batch top-100 by (score desc, flat idx asc) — matches lax.top_k ties
// ---------------------------------------------------------------------------
__global__ __launch_bounds__(1024) void topk_kernel(
    const float* __restrict__ cscore, const int* __restrict__ cidx,
    const int* __restrict__ counts, const float* __restrict__ sigma,
    float* __restrict__ out)
{
    __shared__ float sc[CAP];
    __shared__ int   si[CAP];
    __shared__ float rs[16];
    __shared__ int   ri[16];
    __shared__ int   rp[16];

    const int b    = blockIdx.x;
    const int tid  = threadIdx.x;
    const int wid  = tid >> 6;
    const int lane = tid & 63;

    int cnt = counts[b];
    if (cnt > CAP) cnt = CAP;

    for (int i = tid; i < cnt; i += 1024) {
        sc[i] = cscore[b * CAP + i];
        si[i] = cidx[b * CAP + i];
    }
    __syncthreads();

    for (int k = 0; k < KTOP; ++k) {
        float bs = -FLT_MAX;
        int   bi = 0x7fffffff;
        int   bp = -1;
        for (int i = tid; i < cnt; i += 1024) {
            const float s_ = sc[i];
            const int   id = si[i];
            if (s_ > bs || (s_ == bs && id < bi)) { bs = s_; bi = id; bp = i; }
        }
#pragma unroll
        for (int off = 32; off > 0; off >>= 1) {
            const float os = __shfl_xor(bs, off);
            const int   oi = __shfl_xor(bi, off);
            const int   op = __shfl_xor(bp, off);
            if (os > bs || (os == bs && oi < bi)) { bs = os; bi = oi; bp = op; }
        }
        if (lane == 0) { rs[wid] = bs; ri[wid] = bi; rp[wid] = bp; }
        __syncthreads();
        if (tid == 0) {
            float fb = rs[0]; int fi = ri[0]; int fpos = rp[0];
            for (int wv = 1; wv < 16; ++wv) {
                if (rs[wv] > fb || (rs[wv] == fb && ri[wv] < fi)) {
                    fb = rs[wv]; fi = ri[wv]; fpos = rp[wv];
                }
            }
            float scorev; int flatidx;
            if (fpos < 0) {                 // fewer than K candidates (not expected)
                scorev = NEGV; flatidx = (k - cnt) > 0 ? (k - cnt) : 0;
            } else {
                scorev = fb; flatidx = fi;
                sc[fpos] = -FLT_MAX;        // remove winner
            }
            int sidx = flatidx / HW;
            if (sidx < 0) sidx = 0; if (sidx > S_ - 1) sidx = S_ - 1;
            const int sp = flatidx - (flatidx / HW) * HW;
            const int yy = sp / W_;
            const int xx = sp - yy * W_;
            out[b * KTOP + k]                  = fmaxf(scorev, 0.f);
            out[800 + (b * KTOP + k) * 2 + 0]  = (float)xx / (float)W_;
            out[800 + (b * KTOP + k) * 2 + 1]  = (float)yy / (float)H_;
            out[2400 + b * KTOP + k]           = sigma[sidx];
            out[3200 + b * KTOP + k]           = (float)sp;
        }
        __syncthreads();
    }
}

__global__ void init_counts_kernel(int* counts)
{
    if (threadIdx.x < B_) counts[threadIdx.x] = 0;
}

extern "C" void kernel_launch(void* const* d_in, const int* in_sizes, int n_in,
                              void* d_out, int out_size, void* d_ws, size_t ws_size,
                              hipStream_t stream)
{
    const float* feats = (const float*)d_in[0];
    const float* sigma = (const float*)d_in[1];
    const float* w1    = (const float*)d_in[2];
    const float* b1    = (const float*)d_in[3];
    const float* w2    = (const float*)d_in[4];
    const float* b2    = (const float*)d_in[5];
    float* out = (float*)d_out;

    char* ws = (char*)d_ws;
    float* resp   = (float*)ws;
    int*   counts = (int*)(ws + (size_t)NPIX * 4);
    float* cscore = (float*)(ws + (size_t)NPIX * 4 + 64);
    int*   cidx   = (int*)(ws + (size_t)NPIX * 4 + 64 + (size_t)B_ * CAP * 4);

    init_counts_kernel<<<1, 64, 0, stream>>>(counts);
    resp_kernel<<<2304, 256, 0, stream>>>(feats, sigma, w1, b1, w2, b2, resp);
    peak_kernel<<<NPIX / 256, 256, 0, stream>>>(resp, counts, cscore, cidx);
    topk_kernel<<<B_, 1024, 0, stream>>>(cscore, cidx, counts, sigma, out);
}

// Round 5
// 672.698 us; speedup vs baseline: 1.7302x; 1.7302x over previous
//
#include <hip/hip_runtime.h>
#include <cstdint>
#include <cfloat>
#include <cstddef>

#define C_   128
#define CH   64
#define B_   8
#define S_   6
#define H_   128
#define W_   192
#define HW   (H_*W_)          /* 24576 */
#define SHW  (S_*HW)          /* 147456 */
#define NPIX (B_*SHW)         /* 1179648 */
#define KTOP 100
#define CAP  6144
#define NEGV (-1e9f)
#define EPSV (1e-6f)
#define CPAD 64               /* counts padded: one counter per 256B */

// ---------------------------------------------------------------------------
// K1: resp[b,s,y,x] = sigma[s]^2 * ( w2 . relu(W1 @ feat + b1) + b2 )
// 2 pixels per thread (float2 loads), W1 transposed in LDS for broadcast reads.
// (unchanged from Round 4 — known absmax=0; will diagnose with counters next)
// ---------------------------------------------------------------------------
__global__ __launch_bounds__(256) void resp_kernel(
    const float* __restrict__ feats, const float* __restrict__ sigma,
    const float* __restrict__ w1, const float* __restrict__ b1,
    const float* __restrict__ w2, const float* __restrict__ b2,
    float* __restrict__ resp)
{
    __shared__ float w1t[C_ * CH];   // [c][o]
    __shared__ float b1s[CH];
    __shared__ float w2s[CH];

    for (int i = threadIdx.x; i < C_ * CH; i += 256) {
        int o = i & (CH - 1);
        int c = i >> 6;
        w1t[i] = w1[o * C_ + c];
    }
    if (threadIdx.x < CH) {
        b1s[threadIdx.x] = b1[threadIdx.x];
        w2s[threadIdx.x] = w2[threadIdx.x];
    }
    __syncthreads();

    const int plane = blockIdx.x / 48;              // b*S + s
    const int p0    = (blockIdx.x % 48) * 512 + threadIdx.x * 2;
    const float* fp = feats + (size_t)plane * (size_t)(C_ * HW) + p0;

    float2 acc[CH];
#pragma unroll
    for (int o = 0; o < CH; ++o) { acc[o].x = 0.f; acc[o].y = 0.f; }

#pragma unroll 2
    for (int c = 0; c < C_; ++c) {
        const float2 f = *reinterpret_cast<const float2*>(fp + c * HW);
#pragma unroll
        for (int o = 0; o < CH; o += 4) {
            const float4 w = *reinterpret_cast<const float4*>(&w1t[(c << 6) + o]);
            acc[o + 0].x += w.x * f.x;  acc[o + 0].y += w.x * f.y;
            acc[o + 1].x += w.y * f.x;  acc[o + 1].y += w.y * f.y;
            acc[o + 2].x += w.z * f.x;  acc[o + 2].y += w.z * f.y;
            acc[o + 3].x += w.w * f.x;  acc[o + 3].y += w.w * f.y;
        }
    }

    const float b2v = b2[0];
    float rx = b2v, ry = b2v;
#pragma unroll
    for (int o = 0; o < CH; ++o) {
        float hx = fmaxf(acc[o].x + b1s[o], 0.f);
        float hy = fmaxf(acc[o].y + b1s[o], 0.f);
        rx += w2s[o] * hx;
        ry += w2s[o] * hy;
    }
    const int   s   = plane % S_;
    const float sg  = sigma[s];
    const float sg2 = sg * sg;
    float2 outv; outv.x = rx * sg2; outv.y = ry * sg2;
    *reinterpret_cast<float2*>(resp + (size_t)plane * HW + p0) = outv;
}

// ---------------------------------------------------------------------------
// K2: 3x3x3 local max -> candidates. Per-block LDS aggregation, ONE global
// atomic per block, counters padded to separate cache lines (fix for the
// 506us cross-XCD same-line atomic serialization seen in Round 4).
// ---------------------------------------------------------------------------
__global__ __launch_bounds__(256) void peak_kernel(
    const float* __restrict__ resp, int* __restrict__ counts,
    float* __restrict__ cscore, int* __restrict__ cidx)
{
    __shared__ int   lcount;
    __shared__ int   lbase;
    __shared__ float lsc[256];
    __shared__ int   lsi[256];

    if (threadIdx.x == 0) lcount = 0;
    __syncthreads();

    const int gid = blockIdx.x * 256 + threadIdx.x;   // grid covers NPIX exactly
    const int b   = gid / SHW;                        // uniform per block
    const int rem = gid - b * SHW;
    const int s   = rem / HW;                         // uniform per block
    const int p   = rem - s * HW;
    const int y   = p / W_;
    const int x   = p - y * W_;

    const float v = resp[gid];
    bool win = false;
    if (v > 0.f) {                         // is_peak requires resp > 0
        float m = NEGV;
        for (int ds = -1; ds <= 1; ++ds) {
            const int ss = s + ds;
            if (ss < 0 || ss >= S_) continue;   // NEG padding contributes nothing
            for (int dy = -1; dy <= 1; ++dy) {
                const int yy = y + dy;
                if (yy < 0 || yy >= H_) continue;
                for (int dx = -1; dx <= 1; ++dx) {
                    const int xx = x + dx;
                    if (xx < 0 || xx >= W_) continue;
                    m = fmaxf(m, resp[(b * S_ + ss) * HW + yy * W_ + xx]);
                }
            }
        }
        // m includes v itself, so m >= v and |v - m| = m - v
        win = (m - v < EPSV);
    }

    if (win) {
        const int lp = atomicAdd(&lcount, 1);   // LDS atomic — cheap
        lsc[lp] = v;
        lsi[lp] = s * HW + p;
    }
    __syncthreads();
    if (threadIdx.x == 0 && lcount > 0)
        lbase = atomicAdd(&counts[b * CPAD], lcount);  // one atomic/block, padded line
    __syncthreads();
    const int n = lcount;
    for (int i = threadIdx.x; i < n; i += 256) {
        const int pos = lbase + i;
        if (pos < CAP) {
            cscore[b * CAP + pos] = lsc[i];
            cidx[b * CAP + pos]   = lsi[i];
        }
    }
}

// ---------------------------------------------------------------------------
// K3: per-batch top-100 by (score desc, flat idx asc) — matches lax.top_k ties
// ---------------------------------------------------------------------------
__global__ __launch_bounds__(1024) void topk_kernel(
    const float* __restrict__ cscore, const int* __restrict__ cidx,
    const int* __restrict__ counts, const float* __restrict__ sigma,
    float* __restrict__ out)
{
    __shared__ float sc[CAP];
    __shared__ int   si[CAP];
    __shared__ float rs[16];
    __shared__ int   ri[16];
    __shared__ int   rp[16];

    const int b    = blockIdx.x;
    const int tid  = threadIdx.x;
    const int wid  = tid >> 6;
    const int lane = tid & 63;

    int cnt = counts[b * CPAD];
    if (cnt > CAP) cnt = CAP;

    for (int i = tid; i < cnt; i += 1024) {
        sc[i] = cscore[b * CAP + i];
        si[i] = cidx[b * CAP + i];
    }
    __syncthreads();

    for (int k = 0; k < KTOP; ++k) {
        float bs = -FLT_MAX;
        int   bi = 0x7fffffff;
        int   bp = -1;
        for (int i = tid; i < cnt; i += 1024) {
            const float s_ = sc[i];
            const int   id = si[i];
            if (s_ > bs || (s_ == bs && id < bi)) { bs = s_; bi = id; bp = i; }
        }
#pragma unroll
        for (int off = 32; off > 0; off >>= 1) {
            const float os = __shfl_xor(bs, off);
            const int   oi = __shfl_xor(bi, off);
            const int   op = __shfl_xor(bp, off);
            if (os > bs || (os == bs && oi < bi)) { bs = os; bi = oi; bp = op; }
        }
        if (lane == 0) { rs[wid] = bs; ri[wid] = bi; rp[wid] = bp; }
        __syncthreads();
        if (tid == 0) {
            float fb = rs[0]; int fi = ri[0]; int fpos = rp[0];
            for (int wv = 1; wv < 16; ++wv) {
                if (rs[wv] > fb || (rs[wv] == fb && ri[wv] < fi)) {
                    fb = rs[wv]; fi = ri[wv]; fpos = rp[wv];
                }
            }
            float scorev; int flatidx;
            if (fpos < 0) {                 // fewer than K candidates (not expected)
                scorev = NEGV; flatidx = (k - cnt) > 0 ? (k - cnt) : 0;
            } else {
                scorev = fb; flatidx = fi;
                sc[fpos] = -FLT_MAX;        // remove winner
            }
            int sidx = flatidx / HW;
            if (sidx < 0) sidx = 0; if (sidx > S_ - 1) sidx = S_ - 1;
            const int sp = flatidx - (flatidx / HW) * HW;
            const int yy = sp / W_;
            const int xx = sp - yy * W_;
            out[b * KTOP + k]                  = fmaxf(scorev, 0.f);
            out[800 + (b * KTOP + k) * 2 + 0]  = (float)xx / (float)W_;
            out[800 + (b * KTOP + k) * 2 + 1]  = (float)yy / (float)H_;
            out[2400 + b * KTOP + k]           = sigma[sidx];
            out[3200 + b * KTOP + k]           = (float)sp;
        }
        __syncthreads();
    }
}

__global__ void init_counts_kernel(int* counts)
{
    for (int i = threadIdx.x; i < B_ * CPAD; i += 256) counts[i] = 0;
}

extern "C" void kernel_launch(void* const* d_in, const int* in_sizes, int n_in,
                              void* d_out, int out_size, void* d_ws, size_t ws_size,
                              hipStream_t stream)
{
    const float* feats = (const float*)d_in[0];
    const float* sigma = (const float*)d_in[1];
    const float* w1    = (const float*)d_in[2];
    const float* b1    = (const float*)d_in[3];
    const float* w2    = (const float*)d_in[4];
    const float* b2    = (const float*)d_in[5];
    float* out = (float*)d_out;

    char* ws = (char*)d_ws;
    float* resp   = (float*)ws;
    int*   counts = (int*)(ws + (size_t)NPIX * 4);                       // B_*CPAD ints
    float* cscore = (float*)(ws + (size_t)NPIX * 4 + (size_t)B_ * CPAD * 4);
    int*   cidx   = (int*)(ws + (size_t)NPIX * 4 + (size_t)B_ * CPAD * 4
                              + (size_t)B_ * CAP * 4);

    init_counts_kernel<<<1, 256, 0, stream>>>(counts);
    resp_kernel<<<2304, 256, 0, stream>>>(feats, sigma, w1, b1, w2, b2, resp);
    peak_kernel<<<NPIX / 256, 256, 0, stream>>>(resp, counts, cscore, cidx);
    topk_kernel<<<B_, 1024, 0, stream>>>(cscore, cidx, counts, sigma, out);
}